// Round 3
// baseline (92.573 us; speedup 1.0000x reference)
//
#include <hip/hip_runtime.h>

// 2-layer tanh RNN, INP=6, HID=8, B=4096, T=512, + linear head to 1.
// 8 lanes per batch element; lane j owns hidden unit j of both layers.
// State is kept in GATHERED form: g1[m] = h1[j^m], g2[m] = h2[j^m] live in
// registers across steps, so every dot product (whh0, wih1, whh1, head) is a
// pure per-lane FMA chain; each state is gathered exactly once per step
// (7 DPP) right after its tanh. Layers are skewed one step (iteration u does
// layer1+head for u and layer0 for u+1) so the two tanh chains are
// independent and the scheduler can overlap them.

#define INP 6
#define HID 8
#define BATCH 4096
#define TT 512

// DPP controls
#define DPP_XOR1 0xB1   // quad_perm(1,0,3,2): lane ^ 1
#define DPP_XOR2 0x4E   // quad_perm(2,3,0,1): lane ^ 2
#define DPP_XOR3 0x1B   // quad_perm(3,2,1,0): lane ^ 3
#define DPP_HMIR 0x141  // row_half_mirror:    lane ^ 7 (within 8)

template<int CTRL>
__device__ __forceinline__ float fdpp(float v) {
    return __int_as_float(__builtin_amdgcn_update_dpp(
        0, __float_as_int(v), CTRL, 0xF, 0xF, true));
}

// gather own-unit value h into g[m] = h[j^m] (7 DPP, depth 2)
__device__ __forceinline__ void gather8(float (&g)[HID], float h) {
    g[0] = h;
    g[1] = fdpp<DPP_XOR1>(h);
    g[2] = fdpp<DPP_XOR2>(h);
    g[3] = fdpp<DPP_XOR3>(h);
    float g7 = fdpp<DPP_HMIR>(h);   // h[j^7]
    g[7] = g7;
    g[4] = fdpp<DPP_XOR3>(g7);      // h[j^4]
    g[5] = fdpp<DPP_XOR2>(g7);      // h[j^5]
    g[6] = fdpp<DPP_XOR1>(g7);      // h[j^6]
}

// 8-term dot, two chains for ILP
__device__ __forceinline__ float dotg(const float (&w)[HID], const float (&g)[HID]) {
    float a = w[0] * g[0];
    float b = w[1] * g[1];
    a = fmaf(w[2], g[2], a); b = fmaf(w[3], g[3], b);
    a = fmaf(w[4], g[4], a); b = fmaf(w[5], g[5], b);
    a = fmaf(w[6], g[6], a); b = fmaf(w[7], g[7], b);
    return a + b;
}

// tanh(z) = 1 - 2/(exp2(z*2/ln2)+1); exact saturation at +/-inf
__device__ __forceinline__ float ftanh(float z) {
    float e = __builtin_amdgcn_exp2f(z * 2.885390082f);
    return 1.0f - 2.0f * __builtin_amdgcn_rcpf(e + 1.0f);
}

__global__ __launch_bounds__(128) void rnn_fused(
    const float* __restrict__ x,
    const float* __restrict__ Wih0, const float* __restrict__ Whh0,
    const float* __restrict__ bih0, const float* __restrict__ bhh0,
    const float* __restrict__ Wih1, const float* __restrict__ Whh1,
    const float* __restrict__ bih1, const float* __restrict__ bhh1,
    const float* __restrict__ Wout, const float* __restrict__ bout,
    float* __restrict__ out)
{
    const int gtid = blockIdx.x * blockDim.x + threadIdx.x;
    const int b = gtid >> 3;   // batch element
    const int j = gtid & 7;    // hidden unit owned by this lane

    // per-lane weight rows; recurrent/projection rows stored XOR-permuted
    // so slot m multiplies g[m] = h[j^m].
    float wih0[INP], whh0p[HID], wih1p[HID], whh1p[HID], wop[HID];
#pragma unroll
    for (int d = 0; d < INP; d++) wih0[d] = Wih0[j * INP + d];
#pragma unroll
    for (int M = 0; M < HID; M++) {
        whh0p[M] = Whh0[j * HID + (j ^ M)];
        wih1p[M] = Wih1[j * HID + (j ^ M)];
        whh1p[M] = Whh1[j * HID + (j ^ M)];
        wop[M]   = Wout[j ^ M];
    }
    const float b0 = bih0[j] + bhh0[j];
    const float b1 = bih1[j] + bhh1[j];
    const float bo = bout[0];

    const float* xb = x + (size_t)b * TT * INP;
    float* ob = out + (size_t)b * TT;

    float g1[HID], g2[HID];
#pragma unroll
    for (int m = 0; m < HID; m++) { g1[m] = 0.0f; g2[m] = 0.0f; }

    float xsA[48], xsB[48];   // 8 timesteps of x, double-buffered

    auto loadblk = [&](float (&xs)[48], int t0) {
#pragma unroll
        for (int u = 0; u < 24; u++) {
            float2 v = *reinterpret_cast<const float2*>(xb + t0 * INP + u * 2);
            xs[2 * u] = v.x;
            xs[2 * u + 1] = v.y;
        }
        // pin staged values in VGPRs so the loads can't be sunk into the chain
#pragma unroll
        for (int u = 0; u < 48; u++) asm volatile("" : "+v"(xs[u]));
    };

    // layer0 for one timestep given its x slice; updates g1
    auto l0 = [&](const float* xt) {
        float a = b0;
#pragma unroll
        for (int d = 0; d < INP; d++) a = fmaf(wih0[d], xt[d], a);
        a += dotg(whh0p, g1);
        gather8(g1, ftanh(a));
    };

    // block u0: layer1+head for u = u0..u0+7, layer0 for t = u+1 (skip t==TT).
    // xc holds x for t = u0..u0+7, xn for t = u0+8..u0+15.
    auto compute8 = [&](const float (&xc)[48], const float (&xn)[48], int u0,
                        bool last) {
        float oreg = 0.0f;
#pragma unroll
        for (int s = 0; s < 8; s++) {
            // layer1 for u = u0+s: uses g1 = gathered h1(u), g2 = h2(u-1)
            float a1 = b1 + dotg(wih1p, g1) + dotg(whh1p, g2);
            gather8(g2, ftanh(a1));
            // head: full dot on gathered h2(u), uniform across the group
            float o = dotg(wop, g2);
            oreg = (j == s) ? o : oreg;
            // layer0 for t = u+1 (reads the same g1 = h1(u), then overwrites)
            if (!(last && s == 7))
                l0((s < 7) ? &xc[(s + 1) * INP] : &xn[0]);
        }
        ob[u0 + j] = oreg + bo;   // coalesced 8-wide store per group
    };

    // prologue: layer0 for t=0 (g1 is zero, so whh-dot vanishes but is cheap)
    loadblk(xsA, 0);
    l0(&xsA[0]);

    for (int u0 = 0; u0 < TT; u0 += 16) {
        loadblk(xsB, u0 + 8);
        compute8(xsA, xsB, u0, false);
        if (u0 + 16 < TT) loadblk(xsA, u0 + 16);
        compute8(xsB, xsA, u0 + 8, u0 + 16 >= TT);
    }
}

extern "C" void kernel_launch(void* const* d_in, const int* in_sizes, int n_in,
                              void* d_out, int out_size, void* d_ws, size_t ws_size,
                              hipStream_t stream) {
    const float* x    = (const float*)d_in[0];
    const float* Wih0 = (const float*)d_in[1];
    const float* Whh0 = (const float*)d_in[2];
    const float* bih0 = (const float*)d_in[3];
    const float* bhh0 = (const float*)d_in[4];
    const float* Wih1 = (const float*)d_in[5];
    const float* Whh1 = (const float*)d_in[6];
    const float* bih1 = (const float*)d_in[7];
    const float* bhh1 = (const float*)d_in[8];
    const float* Wout = (const float*)d_in[9];
    const float* bout = (const float*)d_in[10];
    float* out = (float*)d_out;

    const int threads = BATCH * HID;   // 32768: 8 lanes per batch element
    const int block = 128;
    const int grid = threads / block;  // 256

    rnn_fused<<<grid, block, 0, stream>>>(x, Wih0, Whh0, bih0, bhh0,
                                          Wih1, Whh1, bih1, bhh1,
                                          Wout, bout, out);
}

// Round 4
// 87.381 us; speedup vs baseline: 1.0594x; 1.0594x over previous
//
#include <hip/hip_runtime.h>

// 2-layer tanh RNN, INP=6, HID=8, B=4096, T=512, + linear head to 1.
// 8 lanes per batch element; lane j owns hidden unit j of both layers.
// Per step: gather h1(t) and h2(t-1) once (14 DPP, VALU pipe) into pairs;
// layer1's two dots run as 8 packed v_pk_fma_f32; the same h1-gather feeds
// layer0(t+1)'s recurrent dot (layer skew). Head = DPP butterfly.
// x is double-buffered in registers with the pin placed AFTER an
// intervening 8-step compute block so global-load latency is hidden.

#define INP 6
#define HID 8
#define BATCH 4096
#define TT 512

// DPP controls
#define DPP_XOR1 0xB1   // quad_perm(1,0,3,2): lane ^ 1
#define DPP_XOR2 0x4E   // quad_perm(2,3,0,1): lane ^ 2
#define DPP_XOR3 0x1B   // quad_perm(3,2,1,0): lane ^ 3
#define DPP_HMIR 0x141  // row_half_mirror:    lane ^ 7 (within 8)

typedef float v2f __attribute__((ext_vector_type(2)));

template<int CTRL>
__device__ __forceinline__ float fdpp(float v) {
    return __int_as_float(__builtin_amdgcn_update_dpp(
        0, __float_as_int(v), CTRL, 0xF, 0xF, true));
}

// tanh(z) = 1 - 2/(exp2(z*2/ln2)+1); exact saturation at +/-inf
__device__ __forceinline__ float ftanh(float z) {
    float e = __builtin_amdgcn_exp2f(z * 2.885390082f);
    return fmaf(-2.0f, __builtin_amdgcn_rcpf(e + 1.0f), 1.0f);
}

__global__ __launch_bounds__(128) void rnn_fused(
    const float* __restrict__ x,
    const float* __restrict__ Wih0, const float* __restrict__ Whh0,
    const float* __restrict__ bih0, const float* __restrict__ bhh0,
    const float* __restrict__ Wih1, const float* __restrict__ Whh1,
    const float* __restrict__ bih1, const float* __restrict__ bhh1,
    const float* __restrict__ Wout, const float* __restrict__ bout,
    float* __restrict__ out)
{
    const int gtid = blockIdx.x * blockDim.x + threadIdx.x;
    const int b = gtid >> 3;   // batch element
    const int j = gtid & 7;    // hidden unit owned by this lane

    // per-lane weight rows; recurrent/projection rows stored XOR-permuted
    // so slot m multiplies h[j^m]. w1p packs (Wih1, Whh1) for pk_fma.
    float wih0[INP], whh0p[HID];
    v2f w1p[HID];
#pragma unroll
    for (int d = 0; d < INP; d++) wih0[d] = Wih0[j * INP + d];
#pragma unroll
    for (int M = 0; M < HID; M++) {
        whh0p[M] = Whh0[j * HID + (j ^ M)];
        w1p[M].x = Wih1[j * HID + (j ^ M)];
        w1p[M].y = Whh1[j * HID + (j ^ M)];
    }
    const float b0 = bih0[j] + bhh0[j];
    const float b1 = bih1[j] + bhh1[j];
    const float wo = Wout[j];
    const float bo = bout[0];

    const float* xb = x + (size_t)b * TT * INP;
    float* ob = out + (size_t)b * TT;

    float h1 = 0.0f, h2 = 0.0f;   // own-unit state: h1(t), h2(t-1)
    float xsA[48], xsB[48];       // 8 timesteps of x, double-buffered

    auto loadblk = [&](float (&xs)[48], int t0) {
#pragma unroll
        for (int u = 0; u < 12; u++) {
            float4 v = *reinterpret_cast<const float4*>(xb + t0 * INP + u * 4);
            xs[4 * u + 0] = v.x; xs[4 * u + 1] = v.y;
            xs[4 * u + 2] = v.z; xs[4 * u + 3] = v.w;
        }
    };
    auto pin48 = [&](float (&xs)[48]) {
#pragma unroll
        for (int u = 0; u < 48; u++) asm volatile("" : "+v"(xs[u]));
    };

    // layer0 for the first step of a block (fresh h1-gather, 7 DPP)
    auto l0_first = [&](const float (&xs)[48]) {
        float a = b0;
#pragma unroll
        for (int d = 0; d < INP; d++) a = fmaf(wih0[d], xs[d], a);
        float g1 = fdpp<DPP_XOR1>(h1), g2_ = fdpp<DPP_XOR2>(h1);
        float g3 = fdpp<DPP_XOR3>(h1), g7 = fdpp<DPP_HMIR>(h1);
        float g4 = fdpp<DPP_XOR3>(g7), g5 = fdpp<DPP_XOR2>(g7);
        float g6 = fdpp<DPP_XOR1>(g7);
        float c = whh0p[0] * h1,  c2 = whh0p[1] * g1;
        c = fmaf(whh0p[2], g2_, c);  c2 = fmaf(whh0p[3], g3, c2);
        c = fmaf(whh0p[4], g4, c);   c2 = fmaf(whh0p[5], g5, c2);
        c = fmaf(whh0p[6], g6, c);   c2 = fmaf(whh0p[7], g7, c2);
        h1 = ftanh(a + c + c2);
    };

    // steps t0..t0+7: layer1+head for each t, layer0 for t+1 (s<7 only)
    auto compute8 = [&](const float (&xs)[48], int t0) {
        float oreg = 0.0f;
#pragma unroll
        for (int s = 0; s < 8; s++) {
            // gather (h1(t)[j^m], h2(t-1)[j^m]) into pairs
            v2f gp[HID];
            gp[0].x = h1;                 gp[0].y = h2;
            gp[1].x = fdpp<DPP_XOR1>(h1); gp[1].y = fdpp<DPP_XOR1>(h2);
            gp[2].x = fdpp<DPP_XOR2>(h1); gp[2].y = fdpp<DPP_XOR2>(h2);
            gp[3].x = fdpp<DPP_XOR3>(h1); gp[3].y = fdpp<DPP_XOR3>(h2);
            float m17 = fdpp<DPP_HMIR>(h1), m27 = fdpp<DPP_HMIR>(h2);
            gp[7].x = m17;                gp[7].y = m27;
            gp[4].x = fdpp<DPP_XOR3>(m17); gp[4].y = fdpp<DPP_XOR3>(m27);
            gp[5].x = fdpp<DPP_XOR2>(m17); gp[5].y = fdpp<DPP_XOR2>(m27);
            gp[6].x = fdpp<DPP_XOR1>(m17); gp[6].y = fdpp<DPP_XOR1>(m27);

            // layer1: both dots as packed f32 fma, two chains
            v2f acc  = gp[0] * w1p[0];
            v2f acc2 = gp[1] * w1p[1];
            acc  = __builtin_elementwise_fma(gp[2], w1p[2], acc);
            acc2 = __builtin_elementwise_fma(gp[3], w1p[3], acc2);
            acc  = __builtin_elementwise_fma(gp[4], w1p[4], acc);
            acc2 = __builtin_elementwise_fma(gp[5], w1p[5], acc2);
            acc  = __builtin_elementwise_fma(gp[6], w1p[6], acc);
            acc2 = __builtin_elementwise_fma(gp[7], w1p[7], acc2);
            acc += acc2;
            h2 = ftanh(b1 + acc.x + acc.y);

            // head: butterfly sum of wo*h2 within the 8-lane group
            float o = wo * h2;
            o += fdpp<DPP_XOR1>(o);
            o += fdpp<DPP_XOR2>(o);
            o += fdpp<DPP_HMIR>(o);   // quad-uniform by now
            oreg = (j == s) ? o : oreg;

            // layer0 for t+1, reusing the h1-gather (gp[].x)
            if (s < 7) {
                float a = b0;
#pragma unroll
                for (int d = 0; d < INP; d++)
                    a = fmaf(wih0[d], xs[(s + 1) * INP + d], a);
                float c  = whh0p[0] * gp[0].x, c2 = whh0p[1] * gp[1].x;
                c = fmaf(whh0p[2], gp[2].x, c);  c2 = fmaf(whh0p[3], gp[3].x, c2);
                c = fmaf(whh0p[4], gp[4].x, c);  c2 = fmaf(whh0p[5], gp[5].x, c2);
                c = fmaf(whh0p[6], gp[6].x, c);  c2 = fmaf(whh0p[7], gp[7].x, c2);
                h1 = ftanh(a + c + c2);
            }
        }
        ob[t0 + j] = oreg + bo;   // coalesced 8-wide store per group
    };

    // prologue: t=0 layer0 (h1(-1)=0 so recurrent dot vanishes)
    loadblk(xsA, 0);
    pin48(xsA);
    {
        float a = b0;
#pragma unroll
        for (int d = 0; d < INP; d++) a = fmaf(wih0[d], xsA[d], a);
        h1 = ftanh(a);
    }
    loadblk(xsB, 8);

    for (int t0 = 0; t0 < TT; t0 += 16) {
        compute8(xsA, t0);                         // consumes xsA only
        if (t0 + 16 < TT) loadblk(xsA, t0 + 16);   // refill A, 8 steps of cover
        pin48(xsB);
        l0_first(xsB);                             // layer0 for t0+8
        compute8(xsB, t0 + 8);
        if (t0 + 24 < TT) loadblk(xsB, t0 + 24);   // refill B
        pin48(xsA);
        if (t0 + 16 < TT) l0_first(xsA);           // layer0 for t0+16
    }
}

extern "C" void kernel_launch(void* const* d_in, const int* in_sizes, int n_in,
                              void* d_out, int out_size, void* d_ws, size_t ws_size,
                              hipStream_t stream) {
    const float* x    = (const float*)d_in[0];
    const float* Wih0 = (const float*)d_in[1];
    const float* Whh0 = (const float*)d_in[2];
    const float* bih0 = (const float*)d_in[3];
    const float* bhh0 = (const float*)d_in[4];
    const float* Wih1 = (const float*)d_in[5];
    const float* Whh1 = (const float*)d_in[6];
    const float* bih1 = (const float*)d_in[7];
    const float* bhh1 = (const float*)d_in[8];
    const float* Wout = (const float*)d_in[9];
    const float* bout = (const float*)d_in[10];
    float* out = (float*)d_out;

    const int threads = BATCH * HID;   // 32768: 8 lanes per batch element
    const int block = 128;
    const int grid = threads / block;  // 256

    rnn_fused<<<grid, block, 0, stream>>>(x, Wih0, Whh0, bih0, bhh0,
                                          Wih1, Whh1, bih1, bhh1,
                                          Wout, bout, out);
}

// Round 6
// 75.840 us; speedup vs baseline: 1.2206x; 1.1522x over previous
//
#include <hip/hip_runtime.h>

// 2-layer tanh RNN, INP=6, HID=8, B=4096, T=512, + linear head to 1.
// R6: x staged through LDS with async global_load_lds (double-buffered
// 64-step chunks, one counted vmcnt(0) per chunk) so NO global-load latency
// sits on the recurrence. 8 lanes per element (lane j owns unit j), cross-
// lane via DPP, skewed step (one h1-gather feeds layer1(t) and layer0(t+1)).

#define INP 6
#define HID 8
#define TT  512
#define CH  64              // steps per chunk
#define NCH (TT/CH)         // 8 chunks
#define EPW 8               // elements per wave
#define CHF (CH*INP)        // 384 floats per element-chunk
#define BUF (EPW*CHF)       // 3072 floats per LDS buffer

#define DPP_XOR1 0xB1   // quad_perm(1,0,3,2): lane ^ 1
#define DPP_XOR2 0x4E   // quad_perm(2,3,0,1): lane ^ 2
#define DPP_XOR3 0x1B   // quad_perm(3,2,1,0): lane ^ 3
#define DPP_HMIR 0x141  // row_half_mirror:    lane ^ 7 (within 8)

template<int CTRL>
__device__ __forceinline__ float fdpp(float v) {
    return __int_as_float(__builtin_amdgcn_update_dpp(
        0, __float_as_int(v), CTRL, 0xF, 0xF, true));
}

// g[m] = h[j^m] within the 8-lane group (7 DPP, depth 2)
__device__ __forceinline__ void gather8(float (&g)[HID], float h) {
    g[0] = h;
    g[1] = fdpp<DPP_XOR1>(h);
    g[2] = fdpp<DPP_XOR2>(h);
    g[3] = fdpp<DPP_XOR3>(h);
    g[7] = fdpp<DPP_HMIR>(h);
    g[4] = fdpp<DPP_XOR3>(g[7]);
    g[5] = fdpp<DPP_XOR2>(g[7]);
    g[6] = fdpp<DPP_XOR1>(g[7]);
}

__device__ __forceinline__ float dotg(const float (&w)[HID], const float (&g)[HID]) {
    float a = w[0] * g[0], b = w[1] * g[1];
    a = fmaf(w[2], g[2], a); b = fmaf(w[3], g[3], b);
    a = fmaf(w[4], g[4], a); b = fmaf(w[5], g[5], b);
    a = fmaf(w[6], g[6], a); b = fmaf(w[7], g[7], b);
    return a + b;
}

// tanh(z) = 1 - 2/(exp2(z*2/ln2)+1); exact saturation at +/-inf
__device__ __forceinline__ float ftanh(float z) {
    float e = __builtin_amdgcn_exp2f(z * 2.885390082f);
    return fmaf(-2.0f, __builtin_amdgcn_rcpf(e + 1.0f), 1.0f);
}

// async global->LDS, 16B per lane, LDS dst = uniform base + lane*16
__device__ __forceinline__ void gl2lds16(const float* g, float* l) {
    __builtin_amdgcn_global_load_lds(
        (const __attribute__((address_space(1))) void*)g,
        (__attribute__((address_space(3))) void*)l, 16, 0, 0);
}

__global__ __launch_bounds__(64) void rnn_fused(
    const float* __restrict__ x,
    const float* __restrict__ Wih0, const float* __restrict__ Whh0,
    const float* __restrict__ bih0, const float* __restrict__ bhh0,
    const float* __restrict__ Wih1, const float* __restrict__ Whh1,
    const float* __restrict__ bih1, const float* __restrict__ bhh1,
    const float* __restrict__ Wout, const float* __restrict__ bout,
    float* __restrict__ out)
{
    __shared__ float lx[2 * BUF];   // 24.6 KB, double-buffered x chunks

    const int lane = threadIdx.x;     // 0..63
    const int j  = lane & 7;          // hidden unit owned by this lane
    const int el = lane >> 3;         // element slot within the wave
    const int ew0 = blockIdx.x * EPW; // wave's first batch element

    // per-lane weights; recurrent rows XOR-permuted (slot m multiplies h[j^m])
    float wih0[INP], whh0p[HID], wih1p[HID], whh1p[HID];
#pragma unroll
    for (int d = 0; d < INP; d++) wih0[d] = Wih0[j * INP + d];
#pragma unroll
    for (int M = 0; M < HID; M++) {
        whh0p[M] = Whh0[j * HID + (j ^ M)];
        wih1p[M] = Wih1[j * HID + (j ^ M)];
        whh1p[M] = Whh1[j * HID + (j ^ M)];
    }
    const float b0 = bih0[j] + bhh0[j];
    const float b1 = bih1[j] + bhh1[j];
    const float wo = Wout[j];
    const float bo = bout[0];

    const float* xw = x + (size_t)ew0 * (TT * INP);
    float* ob = out + (size_t)(ew0 + el) * TT;

    // stage chunk c1 of all 8 elements into LDS buffer pn (12 x 1KB, linear)
    auto stage = [&](int c1, int pn) {
#pragma unroll
        for (int i = 0; i < 12; ++i) {
            unsigned G = (unsigned)(i * 64 + lane);   // f4 index in chunk
            unsigned e = G / 96u;                     // element slot
            unsigned q = G - e * 96u;                 // f4 within element
            const float* src = xw + (size_t)e * (TT * INP) + c1 * CHF + q * 4;
            gl2lds16(src, &lx[pn * BUF + i * 256]);
        }
    };

    // read 6 floats of one timestep from LDS (3 x float2, 8B-aligned)
    auto pf = [&](float2 (&dst)[3], const float* src) {
        dst[0] = *reinterpret_cast<const float2*>(src);
        dst[1] = *reinterpret_cast<const float2*>(src + 2);
        dst[2] = *reinterpret_cast<const float2*>(src + 4);
    };

    float h1 = 0.0f, h2 = 0.0f;   // own-unit state: h1(t), h2(t-1)
    float2 xv[2][3];              // x(t) regs, parity ping-pong

    // ---- prologue: stage chunk 0, compute h1(0), prime xv[1]=x(1) ----
    stage(0, 0);
    asm volatile("s_waitcnt vmcnt(0)" ::: "memory");
    __builtin_amdgcn_sched_barrier(0);
    {
        const float* rb0 = &lx[el * CHF];
        float2 t0[3]; pf(t0, rb0);
        pf(xv[1], rb0 + 6);
        float a = b0;
        a = fmaf(wih0[0], t0[0].x, a); a = fmaf(wih0[1], t0[0].y, a);
        a = fmaf(wih0[2], t0[1].x, a); a = fmaf(wih0[3], t0[1].y, a);
        a = fmaf(wih0[4], t0[2].x, a); a = fmaf(wih0[5], t0[2].y, a);
        h1 = ftanh(a);   // h1(0); recurrent term is zero
    }

    // layer0 for t+1 given gathered g1 = h1(t)[j^m] and x(t+1)
    auto l0 = [&](const float (&g1)[HID], const float2 (&xin)[3]) {
        float a = b0;
        a = fmaf(wih0[0], xin[0].x, a); a = fmaf(wih0[1], xin[0].y, a);
        a = fmaf(wih0[2], xin[1].x, a); a = fmaf(wih0[3], xin[1].y, a);
        a = fmaf(wih0[4], xin[2].x, a); a = fmaf(wih0[5], xin[2].y, a);
        a += dotg(whh0p, g1);
        h1 = ftanh(a);
    };

    // layer1 + head for phase ph; leaves g1 for the caller's l0
    auto l1head = [&](const float (&g1)[HID], int ph, float& oreg) {
        float g2[HID]; gather8(g2, h2);
        float a1 = b1 + dotg(wih1p, g1) + dotg(whh1p, g2);
        h2 = ftanh(a1);
        float o = wo * h2;
        o += fdpp<DPP_XOR1>(o);
        o += fdpp<DPP_XOR2>(o);
        o += fdpp<DPP_HMIR>(o);
        oreg = (j == ph) ? o : oreg;
    };

    int p = 0;
    for (int c = 0; c < NCH; ++c) {
        if (c < NCH - 1) stage(c + 1, p ^ 1);   // ~64 steps of cover
        const float* rb = &lx[p * BUF + el * CHF];

        // 7 regular 8-step bodies (local t = 8*sb + s, all prefetches in-buf)
        for (int sb = 0; sb < 7; ++sb) {
            const float* rp = rb + sb * 48;
            float oreg = 0.0f;
#pragma unroll
            for (int s = 0; s < 8; ++s) {
                pf(xv[s & 1], rp + 6 * s + 12);       // x(t+2) for next step
                float g1[HID]; gather8(g1, h1);       // h1(t)
                l1head(g1, s, oreg);
                l0(g1, xv[(s & 1) ^ 1]);              // consumes x(t+1)
            }
            ob[c * CH + sb * 8 + j] = oreg + bo;
        }

        // last body (sb=7): steps local 56..63; boundary crossload at s=7
        {
            const float* rp = rb + 7 * 48;
            float oreg = 0.0f;
#pragma unroll
            for (int s = 0; s < 7; ++s) {
                if (s <= 5) pf(xv[s & 1], rp + 6 * s + 12);  // up to x(63)
                float g1[HID]; gather8(g1, h1);
                l1head(g1, s, oreg);
                l0(g1, xv[(s & 1) ^ 1]);
            }
            // s = 7: T = c*64 + 63
            {
                float g1[HID]; gather8(g1, h1);
                l1head(g1, 7, oreg);
                if (c < NCH - 1) {
                    // next chunk's staging finished long ago; drain and cross
                    asm volatile("s_waitcnt vmcnt(0)" ::: "memory");
                    __builtin_amdgcn_sched_barrier(0);
                    const float* nrb = &lx[(p ^ 1) * BUF + el * CHF];
                    pf(xv[0], nrb);        // x(next local 0) -> consumed now
                    pf(xv[1], nrb + 6);    // x(next local 1) -> next s=0
                    l0(g1, xv[0]);
                }
                // c == NCH-1: T=511, no layer0 for t=512
            }
            ob[c * CH + 56 + j] = oreg + bo;
        }
        p ^= 1;
    }
}

extern "C" void kernel_launch(void* const* d_in, const int* in_sizes, int n_in,
                              void* d_out, int out_size, void* d_ws, size_t ws_size,
                              hipStream_t stream) {
    const float* x    = (const float*)d_in[0];
    const float* Wih0 = (const float*)d_in[1];
    const float* Whh0 = (const float*)d_in[2];
    const float* bih0 = (const float*)d_in[3];
    const float* bhh0 = (const float*)d_in[4];
    const float* Wih1 = (const float*)d_in[5];
    const float* Whh1 = (const float*)d_in[6];
    const float* bih1 = (const float*)d_in[7];
    const float* bhh1 = (const float*)d_in[8];
    const float* Wout = (const float*)d_in[9];
    const float* bout = (const float*)d_in[10];
    float* out = (float*)d_out;
    (void)d_ws; (void)ws_size; (void)in_sizes; (void)n_in; (void)out_size;

    // 4096 elements / 8 per wave = 512 blocks of one wave each
    rnn_fused<<<512, 64, 0, stream>>>(x, Wih0, Whh0, bih0, bhh0,
                                      Wih1, Whh1, bih1, bhh1,
                                      Wout, bout, out);
}

// Round 7
// 68.138 us; speedup vs baseline: 1.3586x; 1.1130x over previous
//
#include <hip/hip_runtime.h>

// 2-layer tanh RNN, INP=6, HID=8, B=4096, T=512, + linear head to 1.
// R7: BOTH layers in one register update. 16 lanes per element:
//   lanes 0-7  = h1 units (layer0), lanes 8-15 = h2 units (layer1).
// One 16-lane XOR gather (15 DPP) + one 16-FMA dot + 6 x-FMAs + ONE tanh
// updates h1(t+1) and h2(t) together (natural layer skew).
// x staged via async global_load_lds, element-interleaved at f4 granularity
// (slot = q*4+e) -> conflict-free ds_reads. 4 elements/wave, 1024 waves
// = 1 wave per SIMD, all SIMDs active.

#define INP 6
#define HID 8
#define TT  512
#define CH  64                // steps per chunk
#define NCH (TT/CH)           // 8 chunks
#define EPW 4                 // elements per wave
#define CHF (CH*INP)          // 384 floats per element-chunk
#define BUFF (EPW*CHF)        // 1536 floats per LDS buffer

#define DPP_XOR1 0xB1   // quad_perm(1,0,3,2): lane ^ 1
#define DPP_XOR2 0x4E   // quad_perm(2,3,0,1): lane ^ 2
#define DPP_XOR3 0x1B   // quad_perm(3,2,1,0): lane ^ 3
#define DPP_HMIR 0x141  // row_half_mirror:    lane ^ 7  (within 16-row)
#define DPP_RMIR 0x140  // row_mirror:         lane ^ 15 (within 16-row)

template<int CTRL>
__device__ __forceinline__ float fdpp(float v) {
    return __int_as_float(__builtin_amdgcn_update_dpp(
        0, __float_as_int(v), CTRL, 0xF, 0xF, true));
}

// tanh(z) = 1 - 2/(exp2(z*2/ln2)+1); exact saturation at +/-inf
__device__ __forceinline__ float ftanh(float z) {
    float e = __builtin_amdgcn_exp2f(z * 2.885390082f);
    return fmaf(-2.0f, __builtin_amdgcn_rcpf(e + 1.0f), 1.0f);
}

// async global->LDS, 16B per lane, LDS dst = uniform base + lane*16
__device__ __forceinline__ void gl2lds16(const float* g, float* l) {
    __builtin_amdgcn_global_load_lds(
        (const __attribute__((address_space(1))) void*)g,
        (__attribute__((address_space(3))) void*)l, 16, 0, 0);
}

// g[m] = v[lane ^ m] within each 16-lane row (15 DPP)
#define GATHER16(g, v)                \
    g[0]  = (v);                      \
    g[1]  = fdpp<DPP_XOR1>(v);        \
    g[2]  = fdpp<DPP_XOR2>(v);        \
    g[3]  = fdpp<DPP_XOR3>(v);        \
    g[7]  = fdpp<DPP_HMIR>(v);        \
    g[4]  = fdpp<DPP_XOR3>(g[7]);     \
    g[5]  = fdpp<DPP_XOR2>(g[7]);     \
    g[6]  = fdpp<DPP_XOR1>(g[7]);     \
    g[15] = fdpp<DPP_RMIR>(v);        \
    g[8]  = fdpp<DPP_HMIR>(g[15]);    \
    g[9]  = fdpp<DPP_XOR1>(g[8]);     \
    g[10] = fdpp<DPP_XOR2>(g[8]);     \
    g[11] = fdpp<DPP_XOR3>(g[8]);     \
    g[12] = fdpp<DPP_XOR3>(g[15]);    \
    g[13] = fdpp<DPP_XOR2>(g[15]);    \
    g[14] = fdpp<DPP_XOR1>(g[15]);

// read one timestep's 6 floats (3 x float2) from interleaved LDS layout:
// float f of element el lives at byte 4*(16*(f>>2) + 4*el + (f&3)); BASE
// already includes the el*4 and buffer offset. F0 = t_local*6, even.
#define PF3(dst, base, F0) do {                                                            \
    dst[0] = *reinterpret_cast<const float2*>((base) + ((((F0)+0)>>2)<<4) + (((F0)+0)&3)); \
    dst[1] = *reinterpret_cast<const float2*>((base) + ((((F0)+2)>>2)<<4) + (((F0)+2)&3)); \
    dst[2] = *reinterpret_cast<const float2*>((base) + ((((F0)+4)>>2)<<4) + (((F0)+4)&3)); \
} while (0)

// one fused step: consumes x(t+1) in XC, prefetches into XN from PFBASE at
// PFF0 (compile-time), updates v = (h1(t+1) | h2(t)), head -> oreg if j==S
#define STEP(S, XC, XN, PFBASE, PFF0, DOPF)                      \
  {                                                              \
    if (DOPF) PF3(XN, PFBASE, PFF0);                             \
    float g[16]; GATHER16(g, v);                                 \
    float a0 = fmaf(wx0, XC[0].x, bias);                         \
    float a1 = wx1 * XC[0].y;                                    \
    float a2 = wx2 * XC[1].x;                                    \
    float a3 = wx3 * XC[1].y;                                    \
    a0 = fmaf(wx4, XC[2].x, a0);                                 \
    a1 = fmaf(wx5, XC[2].y, a1);                                 \
    a0 = fmaf(wg[0],  g[0],  a0);  a1 = fmaf(wg[1],  g[1],  a1); \
    a2 = fmaf(wg[2],  g[2],  a2);  a3 = fmaf(wg[3],  g[3],  a3); \
    a0 = fmaf(wg[4],  g[4],  a0);  a1 = fmaf(wg[5],  g[5],  a1); \
    a2 = fmaf(wg[6],  g[6],  a2);  a3 = fmaf(wg[7],  g[7],  a3); \
    a0 = fmaf(wg[8],  g[8],  a0);  a1 = fmaf(wg[9],  g[9],  a1); \
    a2 = fmaf(wg[10], g[10], a2);  a3 = fmaf(wg[11], g[11], a3); \
    a0 = fmaf(wg[12], g[12], a0);  a1 = fmaf(wg[13], g[13], a1); \
    a2 = fmaf(wg[14], g[14], a2);  a3 = fmaf(wg[15], g[15], a3); \
    v = ftanh((a0 + a1) + (a2 + a3));                            \
    float o = wo_l * v;                                          \
    o += fdpp<DPP_XOR1>(o);                                      \
    o += fdpp<DPP_XOR2>(o);                                      \
    o += fdpp<DPP_HMIR>(o);                                      \
    oreg = (j == (S)) ? o : oreg;                                \
  }

__global__ __launch_bounds__(64) void rnn_fused(
    const float* __restrict__ x,
    const float* __restrict__ Wih0, const float* __restrict__ Whh0,
    const float* __restrict__ bih0, const float* __restrict__ bhh0,
    const float* __restrict__ Wih1, const float* __restrict__ Whh1,
    const float* __restrict__ bih1, const float* __restrict__ bhh1,
    const float* __restrict__ Wout, const float* __restrict__ bout,
    float* __restrict__ out)
{
    __shared__ float lx[2 * BUFF];   // 12 KiB, double-buffered x chunks

    const int lane = threadIdx.x;        // 0..63
    const int j    = lane & 7;           // hidden unit owned by this lane
    const int up   = (lane >> 3) & 1;    // 0: h1 row, 1: h2 row
    const int el   = lane >> 4;          // element slot (0..3)
    const int ew0  = blockIdx.x * EPW;   // wave's first batch element

    // per-lane fused weights: lower lanes use Whh0 (m<8) + Wih0 on x;
    // upper lanes use Whh1 (m<8, gathers h2) + Wih1 (m>=8, gathers h1).
    float wg[16];
#pragma unroll
    for (int M = 0; M < 8; ++M)
        wg[M] = up ? Whh1[j * HID + (j ^ M)] : Whh0[j * HID + (j ^ M)];
#pragma unroll
    for (int M = 8; M < 16; ++M)
        wg[M] = up ? Wih1[j * HID + (j ^ (M & 7))] : 0.0f;
    const float wx0 = up ? 0.0f : Wih0[j * INP + 0];
    const float wx1 = up ? 0.0f : Wih0[j * INP + 1];
    const float wx2 = up ? 0.0f : Wih0[j * INP + 2];
    const float wx3 = up ? 0.0f : Wih0[j * INP + 3];
    const float wx4 = up ? 0.0f : Wih0[j * INP + 4];
    const float wx5 = up ? 0.0f : Wih0[j * INP + 5];
    const float bias = up ? (bih1[j] + bhh1[j]) : (bih0[j] + bhh0[j]);
    const float wo_l = up ? Wout[j] : 0.0f;
    const float bo   = bout[0];

    const float* xw = x + (size_t)ew0 * (TT * INP);
    float* ob = out + (size_t)(ew0 + el) * TT;

    // stage chunk c1 (4 elements x 384 floats) into buffer pn, interleaved:
    // LDS f4 slot S = q*4 + e  (e = element, q = f4 index within element)
    auto stage = [&](int c1, int pn) {
#pragma unroll
        for (int i = 0; i < 6; ++i) {
            const int e = lane & 3;
            const int q = i * 16 + (lane >> 2);
            const float* src = xw + (size_t)e * (TT * INP) + c1 * CHF + q * 4;
            gl2lds16(src, &lx[pn * BUFF + i * 256]);
        }
    };

    float v = 0.0f;           // lanes 0-7: h1(t); lanes 8-15: h2(t-1)
    float2 xvA[3], xvB[3];    // x(t) regs: A = even t, B = odd t

    // ---- prologue: stage chunk 0; v = (up ? 0 : h1(0)); prime B=x(1) ----
    stage(0, 0);
    asm volatile("s_waitcnt vmcnt(0)" ::: "memory");
    __builtin_amdgcn_sched_barrier(0);
    {
        const float* rb = &lx[el * 4];
        float2 x0[3];
        PF3(x0, rb, 0);       // x(0)
        PF3(xvB, rb, 6);      // x(1)
        float a = fmaf(wx0, x0[0].x, bias);
        a = fmaf(wx1, x0[0].y, a);
        a = fmaf(wx2, x0[1].x, a);
        a = fmaf(wx3, x0[1].y, a);
        a = fmaf(wx4, x0[2].x, a);
        a = fmaf(wx5, x0[2].y, a);
        float t0v = ftanh(a);
        v = up ? 0.0f : t0v;  // h2(-1) = 0
    }

    for (int c = 0; c < NCH; ++c) {
        const int p = c & 1;
        if (c < NCH - 1) stage(c + 1, p ^ 1);          // ~64 steps of cover
        const float* rb = &lx[p * BUFF + el * 4];
        const float* nb = &lx[(p ^ 1) * BUFF + el * 4];

        for (int sb = 0; sb < 7; ++sb) {
            const float* rp = rb + sb * 192;           // body base (48 floats)
            float oreg = 0.0f;
            STEP(0, xvB, xvA, rp, 12, true)
            STEP(1, xvA, xvB, rp, 18, true)
            STEP(2, xvB, xvA, rp, 24, true)
            STEP(3, xvA, xvB, rp, 30, true)
            STEP(4, xvB, xvA, rp, 36, true)
            STEP(5, xvA, xvB, rp, 42, true)
            STEP(6, xvB, xvA, rp, 48, true)
            STEP(7, xvA, xvB, rp, 54, true)
            if (up) ob[c * CH + sb * 8 + j] = oreg + bo;
        }
        {   // body 7: steps 56..63, crossover into next chunk's buffer
            const float* rp = rb + 7 * 192;
            float oreg = 0.0f;
            STEP(0, xvB, xvA, rp, 12, true)
            STEP(1, xvA, xvB, rp, 18, true)
            STEP(2, xvB, xvA, rp, 24, true)
            STEP(3, xvA, xvB, rp, 30, true)
            STEP(4, xvB, xvA, rp, 36, true)
            STEP(5, xvA, xvB, rp, 42, true)
            if (c < NCH - 1) {
                // next chunk staged long ago; one counted drain per 64 steps
                asm volatile("s_waitcnt vmcnt(0)" ::: "memory");
                __builtin_amdgcn_sched_barrier(0);
                STEP(6, xvB, xvA, nb, 0, true)   // pf x(next 0) -> A (even)
                STEP(7, xvA, xvB, nb, 6, true)   // pf x(next 1) -> B (odd)
            } else {
                // last chunk: x(512) doesn't exist; lower-lane result unused
                STEP(6, xvB, xvA, rp, 0, false)
                STEP(7, xvA, xvB, rp, 0, false)
            }
            if (up) ob[c * CH + 56 + j] = oreg + bo;
        }
    }
}

extern "C" void kernel_launch(void* const* d_in, const int* in_sizes, int n_in,
                              void* d_out, int out_size, void* d_ws, size_t ws_size,
                              hipStream_t stream) {
    const float* x    = (const float*)d_in[0];
    const float* Wih0 = (const float*)d_in[1];
    const float* Whh0 = (const float*)d_in[2];
    const float* bih0 = (const float*)d_in[3];
    const float* bhh0 = (const float*)d_in[4];
    const float* Wih1 = (const float*)d_in[5];
    const float* Whh1 = (const float*)d_in[6];
    const float* bih1 = (const float*)d_in[7];
    const float* bhh1 = (const float*)d_in[8];
    const float* Wout = (const float*)d_in[9];
    const float* bout = (const float*)d_in[10];
    float* out = (float*)d_out;
    (void)d_ws; (void)ws_size; (void)in_sizes; (void)n_in; (void)out_size;

    // 4096 elements / 4 per wave = 1024 single-wave blocks -> 1 wave/SIMD
    rnn_fused<<<1024, 64, 0, stream>>>(x, Wih0, Whh0, bih0, bhh0,
                                       Wih1, Whh1, bih1, bhh1,
                                       Wout, bout, out);
}

// Round 8
// 64.505 us; speedup vs baseline: 1.4351x; 1.0563x over previous
//
#include <hip/hip_runtime.h>

// 2-layer tanh RNN, INP=6, HID=8, B=4096, T=512, + linear head to 1.
// R8: fused both-layers step (16 lanes/element: lanes 0-7 h1, 8-15 h2) with
//  (a) DPP-fused FMAs: single-use fdpp feeding v_fmac -> DPP combiner folds;
//      standalone gathers reduced to 3 depth-1 DPDs (half_mirror, row_ror:8,
//      row_mirror).
//  (b) head computed in LOWER lanes' previously-zero wg[8..15] slots
//      (wg[8+m]=Wout[j^m], g[8+m]=h2(t-1)[j^m]); separate accumulator pair
//      (c0,c1) keeps it out of tanh; stores shift one step later.
// x staged via async global_load_lds, element-interleaved (conflict-free),
// double-buffered 64-step chunks, one counted vmcnt(0) per chunk.

#define INP 6
#define HID 8
#define TT  512
#define CH  64                // steps per chunk
#define NCH (TT/CH)           // 8 chunks
#define EPW 4                 // elements per wave
#define CHF (CH*INP)          // 384 floats per element-chunk
#define BUFF (EPW*CHF)        // 1536 floats per LDS buffer

#define DPP_XOR1 0xB1   // quad_perm(1,0,3,2): lane ^ 1
#define DPP_XOR2 0x4E   // quad_perm(2,3,0,1): lane ^ 2
#define DPP_XOR3 0x1B   // quad_perm(3,2,1,0): lane ^ 3
#define DPP_HMIR 0x141  // row_half_mirror:    lane ^ 7  (within 16-row)
#define DPP_RMIR 0x140  // row_mirror:         lane ^ 15 (within 16-row)
#define DPP_ROR8 0x128  // row_ror:8:          lane ^ 8  (within 16-row)

template<int CTRL>
__device__ __forceinline__ float fdpp(float v) {
    return __int_as_float(__builtin_amdgcn_update_dpp(
        0, __float_as_int(v), CTRL, 0xF, 0xF, true));
}

// tanh(z) = 1 - 2/(exp2(z*2/ln2)+1); exact saturation at +/-inf
__device__ __forceinline__ float ftanh(float z) {
    float e = __builtin_amdgcn_exp2f(z * 2.885390082f);
    return fmaf(-2.0f, __builtin_amdgcn_rcpf(e + 1.0f), 1.0f);
}

// async global->LDS, 16B per lane, LDS dst = uniform base + lane*16
__device__ __forceinline__ void gl2lds16(const float* g, float* l) {
    __builtin_amdgcn_global_load_lds(
        (const __attribute__((address_space(1))) void*)g,
        (__attribute__((address_space(3))) void*)l, 16, 0, 0);
}

// read one timestep's 6 floats (3 x float2) from interleaved LDS layout:
// float f of element el lives at byte 4*(16*(f>>2) + 4*el + (f&3)); BASE
// already includes the el*4 and buffer offset. F0 = t_local*6, even.
#define PF3(dst, base, F0) do {                                                            \
    dst[0] = *reinterpret_cast<const float2*>((base) + ((((F0)+0)>>2)<<4) + (((F0)+0)&3)); \
    dst[1] = *reinterpret_cast<const float2*>((base) + ((((F0)+2)>>2)<<4) + (((F0)+2)&3)); \
    dst[2] = *reinterpret_cast<const float2*>((base) + ((((F0)+4)>>2)<<4) + (((F0)+4)&3)); \
} while (0)

// one fused step. Entry: v = (h1(t) | h2(t-1)). Consumes x(t+1) in XC,
// prefetches into XN. Exit: v = (h1(t+1) | h2(t)). Captures head o(t-1)
// (= s in lower lanes, from gathered h2(t-1)) into oreg where j == (S+7)&7.
#define STEP(S, XC, XN, PFBASE, PFF0, DOPF)                        \
  {                                                                \
    if (DOPF) PF3(XN, PFBASE, PFF0);                               \
    float g7  = fdpp<DPP_HMIR>(v);                                 \
    float g8  = fdpp<DPP_ROR8>(v);                                 \
    float g15 = fdpp<DPP_RMIR>(v);                                 \
    float a0 = fmaf(wx0, XC[0].x, bias);                           \
    float a1 = wx1 * XC[0].y;                                      \
    a0 = fmaf(wx2, XC[1].x, a0);                                   \
    a1 = fmaf(wx3, XC[1].y, a1);                                   \
    a0 = fmaf(wx4, XC[2].x, a0);                                   \
    a1 = fmaf(wx5, XC[2].y, a1);                                   \
    a0 = fmaf(wg[0], v, a0);                                       \
    a1 = fmaf(wg[1], fdpp<DPP_XOR1>(v), a1);                       \
    a0 = fmaf(wg[2], fdpp<DPP_XOR2>(v), a0);                       \
    a1 = fmaf(wg[3], fdpp<DPP_XOR3>(v), a1);                       \
    a0 = fmaf(wg[4], fdpp<DPP_XOR3>(g7), a0);                      \
    a1 = fmaf(wg[5], fdpp<DPP_XOR2>(g7), a1);                      \
    a0 = fmaf(wg[6], fdpp<DPP_XOR1>(g7), a0);                      \
    a1 = fmaf(wg[7], g7, a1);                                      \
    float c0 = wg[8] * g8;                                         \
    float c1 = wg[9] * fdpp<DPP_XOR1>(g8);                         \
    c0 = fmaf(wg[10], fdpp<DPP_XOR2>(g8),  c0);                    \
    c1 = fmaf(wg[11], fdpp<DPP_XOR3>(g8),  c1);                    \
    c0 = fmaf(wg[12], fdpp<DPP_XOR3>(g15), c0);                    \
    c1 = fmaf(wg[13], fdpp<DPP_XOR2>(g15), c1);                    \
    c0 = fmaf(wg[14], fdpp<DPP_XOR1>(g15), c0);                    \
    c1 = fmaf(wg[15], g15, c1);                                    \
    float s   = c0 + c1;                                           \
    float pre = a0 + a1;                                           \
    float tin = fmaf(upf, s, pre);                                 \
    v = ftanh(tin);                                                \
    oreg = (j == (((S) + 7) & 7)) ? s : oreg;                      \
  }

__global__ __launch_bounds__(64) void rnn_fused(
    const float* __restrict__ x,
    const float* __restrict__ Wih0, const float* __restrict__ Whh0,
    const float* __restrict__ bih0, const float* __restrict__ bhh0,
    const float* __restrict__ Wih1, const float* __restrict__ Whh1,
    const float* __restrict__ bih1, const float* __restrict__ bhh1,
    const float* __restrict__ Wout, const float* __restrict__ bout,
    float* __restrict__ out)
{
    __shared__ float lx[2 * BUFF];   // 12 KiB, double-buffered x chunks

    const int lane = threadIdx.x;        // 0..63
    const int j    = lane & 7;           // hidden unit owned by this lane
    const int up   = (lane >> 3) & 1;    // 0: h1 row, 1: h2 row
    const int el   = lane >> 4;          // element slot (0..3)
    const int ew0  = blockIdx.x * EPW;   // wave's first batch element

    // per-lane fused weights:
    //  lower: m<8 -> Whh0 (gathers h1); m>=8 -> Wout[j^m] (head on h2(t-1))
    //  upper: m<8 -> Whh1 (gathers h2); m>=8 -> Wih1 (gathers h1)
    float wg[16];
#pragma unroll
    for (int M = 0; M < 8; ++M)
        wg[M] = up ? Whh1[j * HID + (j ^ M)] : Whh0[j * HID + (j ^ M)];
#pragma unroll
    for (int M = 8; M < 16; ++M)
        wg[M] = up ? Wih1[j * HID + (j ^ (M & 7))] : Wout[j ^ (M & 7)];
    const float wx0 = up ? 0.0f : Wih0[j * INP + 0];
    const float wx1 = up ? 0.0f : Wih0[j * INP + 1];
    const float wx2 = up ? 0.0f : Wih0[j * INP + 2];
    const float wx3 = up ? 0.0f : Wih0[j * INP + 3];
    const float wx4 = up ? 0.0f : Wih0[j * INP + 4];
    const float wx5 = up ? 0.0f : Wih0[j * INP + 5];
    const float bias = up ? (bih1[j] + bhh1[j]) : (bih0[j] + bhh0[j]);
    const float upf  = up ? 1.0f : 0.0f;
    const float bo   = bout[0];

    const float* xw = x + (size_t)ew0 * (TT * INP);
    float* ob = out + (size_t)(ew0 + el) * TT;

    // stage chunk c1 (4 elements x 384 floats) into buffer pn, interleaved:
    // LDS f4 slot S = q*4 + e  (e = element, q = f4 index within element)
    auto stage = [&](int c1, int pn) {
#pragma unroll
        for (int i = 0; i < 6; ++i) {
            const int e = lane & 3;
            const int q = i * 16 + (lane >> 2);
            const float* src = xw + (size_t)e * (TT * INP) + c1 * CHF + q * 4;
            gl2lds16(src, &lx[pn * BUFF + i * 256]);
        }
    };

    float v = 0.0f;           // lanes 0-7: h1(t); lanes 8-15: h2(t-1)
    float oreg = 0.0f;        // lower lanes: head outputs, slot = j
    float2 xvA[3], xvB[3];    // x(t) regs: A = even t, B = odd t

    // ---- prologue: stage chunk 0; v = (up ? 0 : h1(0)); prime B=x(1) ----
    stage(0, 0);
    asm volatile("s_waitcnt vmcnt(0)" ::: "memory");
    __builtin_amdgcn_sched_barrier(0);
    {
        const float* rb = &lx[el * 4];
        float2 x0[3];
        PF3(x0, rb, 0);       // x(0)
        PF3(xvB, rb, 6);      // x(1)
        float a = fmaf(wx0, x0[0].x, bias);
        a = fmaf(wx1, x0[0].y, a);
        a = fmaf(wx2, x0[1].x, a);
        a = fmaf(wx3, x0[1].y, a);
        a = fmaf(wx4, x0[2].x, a);
        a = fmaf(wx5, x0[2].y, a);
        float t0v = ftanh(a);
        v = up ? 0.0f : t0v;  // h2(-1) = 0
    }

    for (int c = 0; c < NCH; ++c) {
        const int p = c & 1;
        if (c < NCH - 1) stage(c + 1, p ^ 1);          // ~64 steps of cover
        const float* rb = &lx[p * BUFF + el * 4];
        const float* nb = &lx[(p ^ 1) * BUFF + el * 4];

        for (int sb = 0; sb < 7; ++sb) {
            const float* rp = rb + sb * 192;           // body base (48 floats)
            STEP(0, xvB, xvA, rp, 12, true)
            // slot 7 just completed the previous 8-step block; store it
            if ((c | sb) && !up) ob[c * CH + sb * 8 - 8 + j] = oreg + bo;
            STEP(1, xvA, xvB, rp, 18, true)
            STEP(2, xvB, xvA, rp, 24, true)
            STEP(3, xvA, xvB, rp, 30, true)
            STEP(4, xvB, xvA, rp, 36, true)
            STEP(5, xvA, xvB, rp, 42, true)
            STEP(6, xvB, xvA, rp, 48, true)
            STEP(7, xvA, xvB, rp, 54, true)
        }
        {   // body 7: steps 56..63, crossover into next chunk's buffer
            const float* rp = rb + 7 * 192;
            STEP(0, xvB, xvA, rp, 12, true)
            if (!up) ob[c * CH + 48 + j] = oreg + bo;   // block sb=6
            STEP(1, xvA, xvB, rp, 18, true)
            STEP(2, xvB, xvA, rp, 24, true)
            STEP(3, xvA, xvB, rp, 30, true)
            STEP(4, xvB, xvA, rp, 36, true)
            STEP(5, xvA, xvB, rp, 42, true)
            if (c < NCH - 1) {
                // next chunk staged long ago; one counted drain per 64 steps
                asm volatile("s_waitcnt vmcnt(0)" ::: "memory");
                __builtin_amdgcn_sched_barrier(0);
                STEP(6, xvB, xvA, nb, 0, true)   // pf x(next 0) -> A (even)
                STEP(7, xvA, xvB, nb, 6, true)   // pf x(next 1) -> B (odd)
            } else {
                // last chunk: x(512) doesn't exist
                STEP(6, xvB, xvA, rp, 0, false)
                STEP(7, xvA, xvB, rp, 0, false)
            }
        }
    }

    // ---- epilogue: head for t = 511 (slot 7), then store final block ----
    {
        float g8  = fdpp<DPP_ROR8>(v);
        float g15 = fdpp<DPP_RMIR>(v);
        float c0 = wg[8] * g8;
        float c1 = wg[9] * fdpp<DPP_XOR1>(g8);
        c0 = fmaf(wg[10], fdpp<DPP_XOR2>(g8),  c0);
        c1 = fmaf(wg[11], fdpp<DPP_XOR3>(g8),  c1);
        c0 = fmaf(wg[12], fdpp<DPP_XOR3>(g15), c0);
        c1 = fmaf(wg[13], fdpp<DPP_XOR2>(g15), c1);
        c0 = fmaf(wg[14], fdpp<DPP_XOR1>(g15), c0);
        c1 = fmaf(wg[15], g15, c1);
        float s = c0 + c1;
        oreg = (j == 7) ? s : oreg;
        if (!up) ob[TT - 8 + j] = oreg + bo;
    }
}

extern "C" void kernel_launch(void* const* d_in, const int* in_sizes, int n_in,
                              void* d_out, int out_size, void* d_ws, size_t ws_size,
                              hipStream_t stream) {
    const float* x    = (const float*)d_in[0];
    const float* Wih0 = (const float*)d_in[1];
    const float* Whh0 = (const float*)d_in[2];
    const float* bih0 = (const float*)d_in[3];
    const float* bhh0 = (const float*)d_in[4];
    const float* Wih1 = (const float*)d_in[5];
    const float* Whh1 = (const float*)d_in[6];
    const float* bih1 = (const float*)d_in[7];
    const float* bhh1 = (const float*)d_in[8];
    const float* Wout = (const float*)d_in[9];
    const float* bout = (const float*)d_in[10];
    float* out = (float*)d_out;
    (void)d_ws; (void)ws_size; (void)in_sizes; (void)n_in; (void)out_size;

    // 4096 elements / 4 per wave = 1024 single-wave blocks -> 1 wave/SIMD
    rnn_fused<<<1024, 64, 0, stream>>>(x, Wih0, Whh0, bih0, bhh0,
                                       Wih1, Whh1, bih1, bhh1,
                                       Wout, bout, out);
}